// Round 12
// baseline (1264.076 us; speedup 1.0000x reference)
//
#include <hip/hip_runtime.h>

#define NATOMS 100000
#define NPAIRS 3200000
// F_ATOM=75, F_PAIR=14, H=50, F_OUT=50

using short8  = __attribute__((ext_vector_type(8))) short;
using float4v = __attribute__((ext_vector_type(4))) float;

__device__ __forceinline__ unsigned short f2bf(float f) {
    unsigned int u = __float_as_uint(f);
    unsigned int r = (u + 0x7fffu + ((u >> 16) & 1u)) >> 16;   // RNE
    return (unsigned short)r;
}
__device__ __forceinline__ float bflo(unsigned int u) { return __uint_as_float(u << 16); }
__device__ __forceinline__ float bfhi(unsigned int u) { return __uint_as_float(u & 0xffff0000u); }
// HW packed f32x2 -> bf16x2 (one VALU op)
__device__ __forceinline__ unsigned int cvtpk(float lo, float hi) {
    unsigned int r;
    asm("v_cvt_pk_bf16_f32 %0, %1, %2" : "=v"(r) : "v"(lo), "v"(hi));
    return r;
}

// software fp8 e4m3 (RNE, denorm->0 flush; |v| << 448 in this workload)
__device__ __forceinline__ unsigned int fp8e(float v) {
    unsigned int u = __float_as_uint(v);
    unsigned int a = u & 0x7fffffffu;
    unsigned int r = a + 0x7FFFFu + ((a >> 20) & 1u);
    int e8 = (int)(r >> 23) - 120;
    unsigned int b = (e8 >= 1) ? (((unsigned int)e8 << 3) | ((r >> 20) & 7u)) : 0u;
    return b | ((u >> 24) & 0x80u);
}
__device__ __forceinline__ float fp8d(unsigned int u, int sh) {
    unsigned int b = (u >> sh) & 0xffu;
    return __uint_as_float((((b & 0x7fu) << 20) + 0x3C000000u) | ((b & 0x80u) << 24));
}

// ws: AA f32[NATOMS*50] | XAu16 u16[NATOMS*64] (fp8: X1' bytes 0..49, X2 bytes 64..113)
//     PAsum f32[NATOMS*50] | WPb u16[64*128] | WPPb/WPAb u16[64*32]

// K0: weight tables + PAsum zeroing (memset folded in)
__global__ __launch_bounds__(256) void k_wconv(
    const float* __restrict__ W_P,  const float* __restrict__ b_P,
    const float* __restrict__ W_PP, const float* __restrict__ b_PP,
    const float* __restrict__ W_PA, const float* __restrict__ b_PA,
    unsigned short* __restrict__ WPb, unsigned short* __restrict__ WPPb,
    unsigned short* __restrict__ WPAb, float* __restrict__ PAsum)
{
    const int idx = blockIdx.x * 256 + threadIdx.x;
    if (idx < 64 * 128) {
        const int n = idx >> 7, k = idx & 127;
        float v = 0.0f;
        if (n < 50) {
            if (k < 50)                  v = W_P[n * 100 + k];
            else if (k == 50)            v = b_P[n];
            else if (k >= 52 && k < 102) v = W_P[n * 100 + 50 + (k - 52)];
        }
        WPb[idx] = f2bf(v);
    }
    if (idx < 64 * 32) {
        const int n = idx >> 5, k = idx & 31;
        float vp = 0.0f, va = 0.0f;
        if (n < 50) {
            if (k < 14)      { vp = W_PP[n * 14 + k]; va = W_PA[n * 14 + k]; }
            else if (k == 14){ vp = b_PP[n];          va = b_PA[n]; }
        }
        WPPb[idx] = f2bf(vp);
        WPAb[idx] = f2bf(va);
    }
    for (int i = idx; i < NATOMS * 50; i += 256 * 256) PAsum[i] = 0.0f;
}

// K1: per-atom precompute; XA now stored as fp8 (u16 = 2 packed fp8).
__global__ __launch_bounds__(256) __attribute__((amdgpu_waves_per_eu(3, 3)))
void k_atom_pre(
    const float* __restrict__ af,
    const float* __restrict__ W_AA, const float* __restrict__ b_AA,
    const float* __restrict__ W_AP, const float* __restrict__ b_AP,
    float* __restrict__ AA, unsigned short* __restrict__ XAu16)
{
    const int a = blockIdx.x * 256 + threadIdx.x;
    if (a >= NATOMS) return;
    const int half = blockIdx.y;

    const float* ar = af + (size_t)a * 75;
    float x[75];
#pragma unroll
    for (int k = 0; k < 75; ++k) x[k] = ar[k];

    const int jbase = half ? 26 : 0;
    const int jend  = half ? 50 : 26;

    float* aout = AA + (size_t)a * 50;
#pragma unroll 2
    for (int j = jbase; j < jend; ++j) {
        const float* wr = W_AA + (size_t)j * 75;
        float acc = b_AA[j];
#pragma unroll
        for (int k = 0; k < 75; ++k) acc = fmaf(x[k], wr[k], acc);
        aout[j] = fmaxf(acc, 0.0f);
    }

    unsigned short* xout = XAu16 + (size_t)a * 64;
    const int nu    = half ? 12 : 13;
    const int ubase = half ? 13 : 0;
#pragma unroll 1
    for (int u = 0; u < nu; ++u) {
        const int j = jbase + 2 * u;
        const float2* w0 = (const float2*)(W_AP + (size_t)j * 150);
        const float2* w1 = (const float2*)(W_AP + (size_t)(j + 1) * 150);
        float a0 = b_AP[j], a1 = b_AP[j + 1];
        float c0 = 0.0f,   c1 = 0.0f;
#pragma unroll
        for (int q = 0; q < 37; ++q) {
            float2 wa = w0[q], wb = w1[q];
            a0 = fmaf(x[2 * q], wa.x, a0); a0 = fmaf(x[2 * q + 1], wa.y, a0);
            a1 = fmaf(x[2 * q], wb.x, a1); a1 = fmaf(x[2 * q + 1], wb.y, a1);
        }
        a0 = fmaf(x[74], ((const float*)w0)[74], a0);
        a1 = fmaf(x[74], ((const float*)w1)[74], a1);
        c0 = fmaf(x[0], ((const float*)w0)[75], c0);
        c1 = fmaf(x[0], ((const float*)w1)[75], c1);
#pragma unroll
        for (int q = 0; q < 37; ++q) {
            float2 wa = ((const float2*)(((const float*)w0) + 76))[q];
            float2 wb = ((const float2*)(((const float*)w1) + 76))[q];
            c0 = fmaf(x[2 * q + 1], wa.x, c0); c0 = fmaf(x[2 * q + 2], wa.y, c0);
            c1 = fmaf(x[2 * q + 1], wb.x, c1); c1 = fmaf(x[2 * q + 2], wb.y, c1);
        }
        xout[ubase + u]      = (unsigned short)(fp8e(a0) | (fp8e(a1) << 8));
        xout[32 + ubase + u] = (unsigned short)(fp8e(c0) | (fp8e(c1) << 8));
    }
}

__device__ __forceinline__ float s_one(unsigned int x1i, unsigned int x2j,
                                       unsigned int x1j, unsigned int x2i, int sh) {
    return fmaxf(fp8d(x1i, sh) + fp8d(x2j, sh), 0.f) +
           fmaxf(fp8d(x1j, sh) + fp8d(x2i, sh), 0.f);
}
// 16 s-values (f = 16c..16c+15) from one uint4 of each source -> 8 bf16-pair slots
__device__ __forceinline__ void s_chunk16(uint4 X1i, uint4 X2j, uint4 X1j, uint4 X2i,
                                          int c, unsigned int* srow, int swz)
{
    const int o = 8 * c;
    srow[(o + 0) ^ swz] = cvtpk(s_one(X1i.x, X2j.x, X1j.x, X2i.x, 0),  s_one(X1i.x, X2j.x, X1j.x, X2i.x, 8));
    srow[(o + 1) ^ swz] = cvtpk(s_one(X1i.x, X2j.x, X1j.x, X2i.x, 16), s_one(X1i.x, X2j.x, X1j.x, X2i.x, 24));
    srow[(o + 2) ^ swz] = cvtpk(s_one(X1i.y, X2j.y, X1j.y, X2i.y, 0),  s_one(X1i.y, X2j.y, X1j.y, X2i.y, 8));
    srow[(o + 3) ^ swz] = cvtpk(s_one(X1i.y, X2j.y, X1j.y, X2i.y, 16), s_one(X1i.y, X2j.y, X1j.y, X2i.y, 24));
    srow[(o + 4) ^ swz] = cvtpk(s_one(X1i.z, X2j.z, X1j.z, X2i.z, 0),  s_one(X1i.z, X2j.z, X1j.z, X2i.z, 8));
    srow[(o + 5) ^ swz] = cvtpk(s_one(X1i.z, X2j.z, X1j.z, X2i.z, 16), s_one(X1i.z, X2j.z, X1j.z, X2i.z, 24));
    srow[(o + 6) ^ swz] = cvtpk(s_one(X1i.w, X2j.w, X1j.w, X2i.w, 0),  s_one(X1i.w, X2j.w, X1j.w, X2i.w, 8));
    srow[(o + 7) ^ swz] = cvtpk(s_one(X1i.w, X2j.w, X1j.w, X2i.w, 16), s_one(X1i.w, X2j.w, X1j.w, X2i.w, 24));
}

// K2: MFMA pair kernel; gather now fp8 (128B rows, 2 lines/row).
__global__ __launch_bounds__(512) void k_pair(
    const float* __restrict__ pf,
    const int* __restrict__ psplit,
    const int* __restrict__ a2p,
    const unsigned short* __restrict__ WPb,
    const unsigned short* __restrict__ WPPb,
    const unsigned short* __restrict__ WPAb,
    const unsigned short* __restrict__ XAu16,
    float* __restrict__ PAsum,
    float* __restrict__ Pout)
{
    // S row (64 u32): 0..24 s, 25 = (1.0,0), 26..50 pp, 51..63 zero
    __shared__ unsigned int  S32[128 * 64];   // 32 KB
    __shared__ unsigned short U16[128 * 64];  // 16 KB
    __shared__ int ps_lds[128];
    __shared__ unsigned char head_list[128];
    __shared__ int nheads;

    const int t   = threadIdx.x;
    const int blk = blockIdx.x;
    const int pl  = t >> 2;
    const int sub = t & 3;
    const int p   = blk * 128 + pl;   // NPAIRS == 25000*128
    const int w   = t >> 6;
    const int l   = t & 63;
    const int lr  = l & 15;
    const int lk  = l >> 4;

    if (t == 0) nheads = 0;
    if (t < 128) ps_lds[t] = psplit[blk * 128 + t];

    // early independent loads
    const int2 ij = ((const int2*)a2p)[p];
    float2 pfa, pfb, pfc, pfd;
    {
        const float2* pr2 = (const float2*)(pf + (size_t)p * 14);
        if (sub == 0) { pfa = pr2[0]; pfb = pr2[1]; pfc = pr2[2]; pfd = pr2[3]; }
        else if (sub == 1) { pfa = pr2[4]; pfb = pr2[5]; pfc = pr2[6]; }
    }

    // fp8 gather (rows 128B; X1' = uint4 0..3, X2 = uint4 4..7)
    const uint4* xi4 = (const uint4*)(XAu16 + (size_t)ij.x * 64);
    const uint4* xj4 = (const uint4*)(XAu16 + (size_t)ij.y * 64);
    uint4 X1i, X1j, X2i, X2j;
    unsigned int t12i = 0, t12j = 0, t28i = 0, t28j = 0;
    if (sub < 3) {
        X1i = xi4[sub];     X1j = xj4[sub];
        X2i = xi4[4 + sub]; X2j = xj4[4 + sub];
    } else {
        const unsigned int* xiu = (const unsigned int*)xi4;
        const unsigned int* xju = (const unsigned int*)xj4;
        t12i = xiu[12]; t12j = xju[12];   // X1 bytes 48,49
        t28i = xiu[28]; t28j = xju[28];   // X2 bytes 112,113
    }

    // stage pf -> U row pl (k0..13 = pf, k14 = 1.0, rest 0)
    {
        uint4 q = {0u, 0u, 0u, 0u};
        if (sub == 0) {
            q.x = cvtpk(pfa.x, pfa.y); q.y = cvtpk(pfb.x, pfb.y);
            q.z = cvtpk(pfc.x, pfc.y); q.w = cvtpk(pfd.x, pfd.y);
        } else if (sub == 1) {
            q.x = cvtpk(pfa.x, pfa.y); q.y = cvtpk(pfb.x, pfb.y);
            q.z = cvtpk(pfc.x, pfc.y); q.w = 0x00003F80u;   // k14=1.0, k15=0
        }
        *(uint4*)((char*)U16 + pl * 128 + ((16 * sub) ^ ((pl & 7) << 4))) = q;
    }

    // s -> S row pl (decode fp8, swizzled bf16-pair writes)
    {
        unsigned int* srow = &S32[pl * 64];
        const int swz = (pl & 7) << 2;
        if (sub < 3) {
            s_chunk16(X1i, X2j, X1j, X2i, sub, srow, swz);
        } else {
            float s48 = s_one(t12i, t28j, t12j, t28i, 0);
            float s49 = s_one(t12i, t28j, t12j, t28i, 8);
            srow[24 ^ swz] = cvtpk(s48, s49);
            srow[25 ^ swz] = 0x00003F80u;   // k50=1.0, k51=0
#pragma unroll
            for (int u = 51; u <= 63; ++u) srow[u ^ swz] = 0u;
        }
    }

    // PP & PA MFMA (A = W tiles, B = pf fragment; D[n][pair])
    {
        const int row  = 16 * w + lr;
        const int swz4 = (row & 7) << 2;
        const short8 bfrag = *(const short8*)((const char*)U16 + row * 128 + ((16 * lk) ^ ((row & 7) << 4)));
        unsigned int* srow = &S32[row * 64];
        unsigned int* U32  = (unsigned int*)U16;

#pragma unroll
        for (int nt = 0; nt < 4; ++nt) {
            short8 afr = *(const short8*)(WPPb + (nt * 16 + lr) * 32 + lk * 8);
            float4v acc = __builtin_amdgcn_mfma_f32_16x16x32_bf16(
                afr, bfrag, (float4v){0.f, 0.f, 0.f, 0.f}, 0, 0, 0);
            const int n0 = nt * 16 + lk * 4;
            if (n0 < 48) {
                uint2 v;
                v.x = cvtpk(fmaxf(acc[0], 0.f), fmaxf(acc[1], 0.f));
                v.y = cvtpk(fmaxf(acc[2], 0.f), fmaxf(acc[3], 0.f));
                *(uint2*)&srow[(26 + (n0 >> 1)) ^ swz4] = v;
            } else if (lk == 0) {
                srow[50 ^ swz4] = cvtpk(fmaxf(acc[0], 0.f), fmaxf(acc[1], 0.f));
            }
        }
#pragma unroll
        for (int nt = 0; nt < 4; ++nt) {
            short8 afr = *(const short8*)(WPAb + (nt * 16 + lr) * 32 + lk * 8);
            float4v acc = __builtin_amdgcn_mfma_f32_16x16x32_bf16(
                afr, bfrag, (float4v){0.f, 0.f, 0.f, 0.f}, 0, 0, 0);
            const int n0 = nt * 16 + lk * 4;
            if (n0 < 48) {
                uint2 v;
                v.x = cvtpk(fmaxf(acc[0], 0.f), fmaxf(acc[1], 0.f));
                v.y = cvtpk(fmaxf(acc[2], 0.f), fmaxf(acc[3], 0.f));
                *(uint2*)&U32[row * 32 + (((n0 >> 1)) ^ swz4)] = v;
            } else if (lk == 0) {
                U32[row * 32 + (24 ^ swz4)] = cvtpk(fmaxf(acc[0], 0.f), fmaxf(acc[1], 0.f));
            }
        }
    }

    // P GEMM: A = WPb tiles, B = S fragments; D[n][pair] -> float2 stores
    {
        const int row = 16 * w + lr;
        short8 sfrag[4];
        const char* srowb = (const char*)&S32[row * 64];
#pragma unroll
        for (int ks = 0; ks < 4; ++ks)
            sfrag[ks] = *(const short8*)(srowb + ((64 * ks + 16 * lk) ^ ((row & 7) << 4)));
        float* po = Pout + ((size_t)blk * 128 + row) * 50;
#pragma unroll
        for (int nt = 0; nt < 4; ++nt) {
            float4v acc = {0.f, 0.f, 0.f, 0.f};
#pragma unroll
            for (int ks = 0; ks < 4; ++ks) {
                short8 wf = *(const short8*)(WPb + (nt * 16 + lr) * 128 + ks * 32 + lk * 8);
                acc = __builtin_amdgcn_mfma_f32_16x16x32_bf16(wf, sfrag[ks], acc, 0, 0, 0);
            }
            const int n0 = nt * 16 + lk * 4;
            if (n0 < 48) {
                float2 v0 = {fmaxf(acc[0], 0.f), fmaxf(acc[1], 0.f)};
                float2 v1 = {fmaxf(acc[2], 0.f), fmaxf(acc[3], 0.f)};
                *(float2*)(po + n0)     = v0;
                *(float2*)(po + n0 + 2) = v1;
            } else if (lk == 0) {
                float2 v0 = {fmaxf(acc[0], 0.f), fmaxf(acc[1], 0.f)};
                *(float2*)(po + 48) = v0;
            }
        }
    }

    // segment-sum of PA; forced heads every 32 rows cap the serial walk
    __syncthreads();
    if (t < 128) {
        bool head = ((t & 31) == 0) || (ps_lds[t] != ps_lds[t - 1]);
        if (head) {
            int idx = atomicAdd(&nheads, 1);
            head_list[idx] = (unsigned char)t;
        }
    }
    __syncthreads();

    const int nh = nheads;
    const unsigned int* U32c = (const unsigned int*)U16;
    for (int iw = t; iw < nh * 25; iw += 512) {
        const int r0  = head_list[iw / 25];
        const int jc  = iw % 25;
        const int seg = ps_lds[r0];
        float a0 = 0.0f, a1 = 0.0f;
        int rr = r0;
        do {
            unsigned int u = U32c[rr * 32 + (jc ^ ((rr & 7) << 2))];
            a0 += bflo(u);
            a1 += bfhi(u);
            ++rr;
        } while (rr < 128 && (rr & 31) != 0 && ps_lds[rr] == seg);
        atomicAdd(&PAsum[(size_t)seg * 50 + 2 * jc],     a0);
        atomicAdd(&PAsum[(size_t)seg * 50 + 2 * jc + 1], a1);
    }
}

// K3: A = relu(concat(AA, PAsum) @ W_A.T + b_A)
__global__ __launch_bounds__(256) __attribute__((amdgpu_waves_per_eu(3, 3)))
void k_atom_final(
    const float* __restrict__ AA, const float* __restrict__ PAsum,
    const float* __restrict__ W_A, const float* __restrict__ b_A,
    float* __restrict__ Aout)
{
    const int a = blockIdx.x * 256 + threadIdx.x;
    if (a >= NATOMS) return;
    const int o0 = blockIdx.y * 25;

    float v[100];
    {
        const float2* p1 = (const float2*)(AA + (size_t)a * 50);
        const float2* p2 = (const float2*)(PAsum + (size_t)a * 50);
#pragma unroll
        for (int q = 0; q < 25; ++q) {
            float2 u1 = p1[q], u2 = p2[q];
            v[2 * q] = u1.x;      v[2 * q + 1] = u1.y;
            v[50 + 2 * q] = u2.x; v[50 + 2 * q + 1] = u2.y;
        }
    }
    float* ao = Aout + (size_t)a * 50;
#pragma unroll 2
    for (int o = o0; o < o0 + 25; ++o) {
        const float4* w4 = (const float4*)(W_A + (size_t)o * 100);
        float acc = b_A[o];
#pragma unroll
        for (int q = 0; q < 25; ++q) {
            float4 w = w4[q];
            acc = fmaf(v[4 * q + 0], w.x, acc);
            acc = fmaf(v[4 * q + 1], w.y, acc);
            acc = fmaf(v[4 * q + 2], w.z, acc);
            acc = fmaf(v[4 * q + 3], w.w, acc);
        }
        ao[o] = fmaxf(acc, 0.0f);
    }
}

extern "C" void kernel_launch(void* const* d_in, const int* in_sizes, int n_in,
                              void* d_out, int out_size, void* d_ws, size_t ws_size,
                              hipStream_t stream)
{
    const float* atom_features = (const float*)d_in[0];
    const float* pair_features = (const float*)d_in[1];
    const int*   pair_split    = (const int*)d_in[2];
    const int*   atom_to_pair  = (const int*)d_in[3];
    const float* W_AA = (const float*)d_in[4];
    const float* b_AA = (const float*)d_in[5];
    const float* W_PA = (const float*)d_in[6];
    const float* b_PA = (const float*)d_in[7];
    const float* W_A  = (const float*)d_in[8];
    const float* b_A  = (const float*)d_in[9];
    const float* W_AP = (const float*)d_in[10];
    const float* b_AP = (const float*)d_in[11];
    const float* W_PP = (const float*)d_in[12];
    const float* b_PP = (const float*)d_in[13];
    const float* W_P  = (const float*)d_in[14];
    const float* b_P  = (const float*)d_in[15];

    float* out   = (float*)d_out;
    float* A_out = out;                              // [NATOMS,50]
    float* P_out = out + (size_t)NATOMS * 50;        // [NPAIRS,50]

    float*          AA    = (float*)d_ws;                                    // 20.0 MB
    unsigned short* XAu16 = (unsigned short*)(AA + (size_t)NATOMS * 50);     // 12.8 MB
    float*          PAsum = (float*)(XAu16 + (size_t)NATOMS * 64);           // 20.0 MB
    unsigned short* WPb   = (unsigned short*)(PAsum + (size_t)NATOMS * 50);  // 16 KB
    unsigned short* WPPb  = WPb + 64 * 128;
    unsigned short* WPAb  = WPPb + 64 * 32;

    k_wconv<<<256, 256, 0, stream>>>(W_P, b_P, W_PP, b_PP, W_PA, b_PA,
                                     WPb, WPPb, WPAb, PAsum);

    k_atom_pre<<<dim3(391, 2), 256, 0, stream>>>(
        atom_features, W_AA, b_AA, W_AP, b_AP, AA, XAu16);

    k_pair<<<NPAIRS / 128, 512, 0, stream>>>(
        pair_features, pair_split, atom_to_pair,
        WPb, WPPb, WPAb, XAu16, PAsum, P_out);

    k_atom_final<<<dim3(391, 2), 256, 0, stream>>>(
        AA, PAsum, W_A, b_A, A_out);
}

// Round 13
// 948.785 us; speedup vs baseline: 1.3323x; 1.3323x over previous
//
#include <hip/hip_runtime.h>

#define NATOMS 100000
#define NPAIRS 3200000
// F_ATOM=75, F_PAIR=14, H=50, F_OUT=50

using short8  = __attribute__((ext_vector_type(8))) short;
using float4v = __attribute__((ext_vector_type(4))) float;
using fx2     = __attribute__((ext_vector_type(2))) float;

__device__ __forceinline__ unsigned short f2bf(float f) {
    unsigned int u = __float_as_uint(f);
    unsigned int r = (u + 0x7fffu + ((u >> 16) & 1u)) >> 16;   // RNE
    return (unsigned short)r;
}
__device__ __forceinline__ float bflo(unsigned int u) { return __uint_as_float(u << 16); }
__device__ __forceinline__ float bfhi(unsigned int u) { return __uint_as_float(u & 0xffff0000u); }
// HW packed f32x2 -> bf16x2 (one VALU op)
__device__ __forceinline__ unsigned int cvtpk(float lo, float hi) {
    unsigned int r;
    asm("v_cvt_pk_bf16_f32 %0, %1, %2" : "=v"(r) : "v"(lo), "v"(hi));
    return r;
}

// software fp8 e4m3 OCP encode (RNE, denorm->0 flush; |v| < 448 here)
__device__ __forceinline__ unsigned int fp8e(float v) {
    unsigned int u = __float_as_uint(v);
    unsigned int a = u & 0x7fffffffu;
    unsigned int r = a + 0x7FFFFu + ((a >> 20) & 1u);
    int e8 = (int)(r >> 23) - 120;
    unsigned int b = (e8 >= 1) ? (((unsigned int)e8 << 3) | ((r >> 20) & 7u)) : 0u;
    return b | ((u >> 24) & 0x80u);
}

// fp8 pair decode: HW v_cvt_pk_f32_fp8 when available (1 op), else software
#if __has_builtin(__builtin_amdgcn_cvt_pk_f32_fp8)
__device__ __forceinline__ fx2 dec8lo(unsigned int u) {
    return __builtin_amdgcn_cvt_pk_f32_fp8((int)u, false);
}
__device__ __forceinline__ fx2 dec8hi(unsigned int u) {
    return __builtin_amdgcn_cvt_pk_f32_fp8((int)u, true);
}
#else
__device__ __forceinline__ float fp8d_(unsigned int u, int sh) {
    unsigned int b = (u >> sh) & 0xffu;
    return __uint_as_float((((b & 0x7fu) << 20) + 0x3C000000u) | ((b & 0x80u) << 24));
}
__device__ __forceinline__ fx2 dec8lo(unsigned int u) { fx2 r; r.x = fp8d_(u, 0);  r.y = fp8d_(u, 8);  return r; }
__device__ __forceinline__ fx2 dec8hi(unsigned int u) { fx2 r; r.x = fp8d_(u, 16); r.y = fp8d_(u, 24); return r; }
#endif

// ws: AA f32[NATOMS*50] | XAu16 u16[NATOMS*64] (fp8: X1' u16 0..24, X2 u16 32..56)
//     PAsum f32[NATOMS*50] | WPb u16[64*128] | WPPb/WPAb u16[64*32]

// K0: weight tables + PAsum zeroing
__global__ __launch_bounds__(256) void k_wconv(
    const float* __restrict__ W_P,  const float* __restrict__ b_P,
    const float* __restrict__ W_PP, const float* __restrict__ b_PP,
    const float* __restrict__ W_PA, const float* __restrict__ b_PA,
    unsigned short* __restrict__ WPb, unsigned short* __restrict__ WPPb,
    unsigned short* __restrict__ WPAb, float* __restrict__ PAsum)
{
    const int idx = blockIdx.x * 256 + threadIdx.x;
    if (idx < 64 * 128) {
        const int n = idx >> 7, k = idx & 127;
        float v = 0.0f;
        if (n < 50) {
            if (k < 50)                  v = W_P[n * 100 + k];
            else if (k == 50)            v = b_P[n];
            else if (k >= 52 && k < 102) v = W_P[n * 100 + 50 + (k - 52)];
        }
        WPb[idx] = f2bf(v);
    }
    if (idx < 64 * 32) {
        const int n = idx >> 5, k = idx & 31;
        float vp = 0.0f, va = 0.0f;
        if (n < 50) {
            if (k < 14)      { vp = W_PP[n * 14 + k]; va = W_PA[n * 14 + k]; }
            else if (k == 14){ vp = b_PP[n];          va = b_PA[n]; }
        }
        WPPb[idx] = f2bf(vp);
        WPAb[idx] = f2bf(va);
    }
    for (int i = idx; i < NATOMS * 50; i += 256 * 256) PAsum[i] = 0.0f;
}

// K1: per-atom precompute; XA stored as fp8. (2,2) — the proven no-spill tier
// (R12's (3,3) regressed the atom pool ~2x).
__global__ __launch_bounds__(256) __attribute__((amdgpu_waves_per_eu(2, 2)))
void k_atom_pre(
    const float* __restrict__ af,
    const float* __restrict__ W_AA, const float* __restrict__ b_AA,
    const float* __restrict__ W_AP, const float* __restrict__ b_AP,
    float* __restrict__ AA, unsigned short* __restrict__ XAu16)
{
    const int a = blockIdx.x * 256 + threadIdx.x;
    if (a >= NATOMS) return;
    const int half = blockIdx.y;

    const float* ar = af + (size_t)a * 75;
    float x[75];
#pragma unroll
    for (int k = 0; k < 75; ++k) x[k] = ar[k];

    const int jbase = half ? 26 : 0;
    const int jend  = half ? 50 : 26;

    float* aout = AA + (size_t)a * 50;
#pragma unroll 2
    for (int j = jbase; j < jend; ++j) {
        const float* wr = W_AA + (size_t)j * 75;
        float acc = b_AA[j];
#pragma unroll
        for (int k = 0; k < 75; ++k) acc = fmaf(x[k], wr[k], acc);
        aout[j] = fmaxf(acc, 0.0f);
    }

    unsigned short* xout = XAu16 + (size_t)a * 64;
    const int nu    = half ? 12 : 13;
    const int ubase = half ? 13 : 0;
#pragma unroll 1
    for (int u = 0; u < nu; ++u) {
        const int j = jbase + 2 * u;
        const float2* w0 = (const float2*)(W_AP + (size_t)j * 150);
        const float2* w1 = (const float2*)(W_AP + (size_t)(j + 1) * 150);
        float a0 = b_AP[j], a1 = b_AP[j + 1];
        float c0 = 0.0f,   c1 = 0.0f;
#pragma unroll
        for (int q = 0; q < 37; ++q) {
            float2 wa = w0[q], wb = w1[q];
            a0 = fmaf(x[2 * q], wa.x, a0); a0 = fmaf(x[2 * q + 1], wa.y, a0);
            a1 = fmaf(x[2 * q], wb.x, a1); a1 = fmaf(x[2 * q + 1], wb.y, a1);
        }
        a0 = fmaf(x[74], ((const float*)w0)[74], a0);
        a1 = fmaf(x[74], ((const float*)w1)[74], a1);
        c0 = fmaf(x[0], ((const float*)w0)[75], c0);
        c1 = fmaf(x[0], ((const float*)w1)[75], c1);
#pragma unroll
        for (int q = 0; q < 37; ++q) {
            float2 wa = ((const float2*)(((const float*)w0) + 76))[q];
            float2 wb = ((const float2*)(((const float*)w1) + 76))[q];
            c0 = fmaf(x[2 * q + 1], wa.x, c0); c0 = fmaf(x[2 * q + 2], wa.y, c0);
            c1 = fmaf(x[2 * q + 1], wb.x, c1); c1 = fmaf(x[2 * q + 2], wb.y, c1);
        }
        xout[ubase + u]      = (unsigned short)(fp8e(a0) | (fp8e(a1) << 8));
        xout[32 + ubase + u] = (unsigned short)(fp8e(c0) | (fp8e(c1) << 8));
    }
}

// one u32 (4 fp8 per stream) -> 2 swizzled bf16-pair slots
__device__ __forceinline__ void s_pair_u32(unsigned int x1i, unsigned int x2j,
    unsigned int x1j, unsigned int x2i, unsigned int* srow, int slot, int swz)
{
    fx2 aL = dec8lo(x1i), bL = dec8lo(x2j), cL = dec8lo(x1j), dL = dec8lo(x2i);
    fx2 aH = dec8hi(x1i), bH = dec8hi(x2j), cH = dec8hi(x1j), dH = dec8hi(x2i);
    float sL0 = fmaxf(aL.x + bL.x, 0.f) + fmaxf(cL.x + dL.x, 0.f);
    float sL1 = fmaxf(aL.y + bL.y, 0.f) + fmaxf(cL.y + dL.y, 0.f);
    float sH0 = fmaxf(aH.x + bH.x, 0.f) + fmaxf(cH.x + dH.x, 0.f);
    float sH1 = fmaxf(aH.y + bH.y, 0.f) + fmaxf(cH.y + dH.y, 0.f);
    srow[(slot)     ^ swz] = cvtpk(sL0, sL1);
    srow[(slot + 1) ^ swz] = cvtpk(sH0, sH1);
}
// 16 s-values from one uint4 of each stream
__device__ __forceinline__ void s_chunk16(uint4 X1i, uint4 X2j, uint4 X1j, uint4 X2i,
                                          int c, unsigned int* srow, int swz)
{
    const int o = 8 * c;
    s_pair_u32(X1i.x, X2j.x, X1j.x, X2i.x, srow, o + 0, swz);
    s_pair_u32(X1i.y, X2j.y, X1j.y, X2i.y, srow, o + 2, swz);
    s_pair_u32(X1i.z, X2j.z, X1j.z, X2i.z, srow, o + 4, swz);
    s_pair_u32(X1i.w, X2j.w, X1j.w, X2i.w, srow, o + 6, swz);
}

// K2: MFMA pair kernel; fp8 gather (128B rows) + HW fp8 decode.
__global__ __launch_bounds__(512) void k_pair(
    const float* __restrict__ pf,
    const int* __restrict__ psplit,
    const int* __restrict__ a2p,
    const unsigned short* __restrict__ WPb,
    const unsigned short* __restrict__ WPPb,
    const unsigned short* __restrict__ WPAb,
    const unsigned short* __restrict__ XAu16,
    float* __restrict__ PAsum,
    float* __restrict__ Pout)
{
    // S row (64 u32): 0..24 s, 25 = (1.0,0), 26..50 pp, 51..63 zero
    __shared__ unsigned int  S32[128 * 64];   // 32 KB
    __shared__ unsigned short U16[128 * 64];  // 16 KB
    __shared__ int ps_lds[128];
    __shared__ unsigned char head_list[128];
    __shared__ int nheads;

    const int t   = threadIdx.x;
    const int blk = blockIdx.x;
    const int pl  = t >> 2;
    const int sub = t & 3;
    const int p   = blk * 128 + pl;   // NPAIRS == 25000*128
    const int w   = t >> 6;
    const int l   = t & 63;
    const int lr  = l & 15;
    const int lk  = l >> 4;

    if (t == 0) nheads = 0;
    if (t < 128) ps_lds[t] = psplit[blk * 128 + t];

    // early independent loads
    const int2 ij = ((const int2*)a2p)[p];
    float2 pfa, pfb, pfc, pfd;
    {
        const float2* pr2 = (const float2*)(pf + (size_t)p * 14);
        if (sub == 0) { pfa = pr2[0]; pfb = pr2[1]; pfc = pr2[2]; pfd = pr2[3]; }
        else if (sub == 1) { pfa = pr2[4]; pfb = pr2[5]; pfc = pr2[6]; }
    }

    // fp8 gather (rows 128B; X1' = uint4 0..3, X2 = uint4 4..7)
    const uint4* xi4 = (const uint4*)(XAu16 + (size_t)ij.x * 64);
    const uint4* xj4 = (const uint4*)(XAu16 + (size_t)ij.y * 64);
    uint4 X1i, X1j, X2i, X2j;
    unsigned int t12i = 0, t12j = 0, t28i = 0, t28j = 0;
    if (sub < 3) {
        X1i = xi4[sub];     X1j = xj4[sub];
        X2i = xi4[4 + sub]; X2j = xj4[4 + sub];
    } else {
        const unsigned int* xiu = (const unsigned int*)xi4;
        const unsigned int* xju = (const unsigned int*)xj4;
        t12i = xiu[12]; t12j = xju[12];   // X1 values 48,49 (low bytes)
        t28i = xiu[28]; t28j = xju[28];   // X2 values 48,49
    }

    // stage pf -> U row pl (k0..13 = pf, k14 = 1.0, rest 0)
    {
        uint4 q = {0u, 0u, 0u, 0u};
        if (sub == 0) {
            q.x = cvtpk(pfa.x, pfa.y); q.y = cvtpk(pfb.x, pfb.y);
            q.z = cvtpk(pfc.x, pfc.y); q.w = cvtpk(pfd.x, pfd.y);
        } else if (sub == 1) {
            q.x = cvtpk(pfa.x, pfa.y); q.y = cvtpk(pfb.x, pfb.y);
            q.z = cvtpk(pfc.x, pfc.y); q.w = 0x00003F80u;   // k14=1.0, k15=0
        }
        *(uint4*)((char*)U16 + pl * 128 + ((16 * sub) ^ ((pl & 7) << 4))) = q;
    }

    // s -> S row pl
    {
        unsigned int* srow = &S32[pl * 64];
        const int swz = (pl & 7) << 2;
        if (sub < 3) {
            s_chunk16(X1i, X2j, X1j, X2i, sub, srow, swz);
        } else {
            fx2 aL = dec8lo(t12i), bL = dec8lo(t28j), cL = dec8lo(t12j), dL = dec8lo(t28i);
            float s48 = fmaxf(aL.x + bL.x, 0.f) + fmaxf(cL.x + dL.x, 0.f);
            float s49 = fmaxf(aL.y + bL.y, 0.f) + fmaxf(cL.y + dL.y, 0.f);
            srow[24 ^ swz] = cvtpk(s48, s49);
            srow[25 ^ swz] = 0x00003F80u;   // k50=1.0, k51=0
#pragma unroll
            for (int u = 51; u <= 63; ++u) srow[u ^ swz] = 0u;
        }
    }

    // PP & PA MFMA (A = W tiles, B = pf fragment; D[n][pair])
    {
        const int row  = 16 * w + lr;
        const int swz4 = (row & 7) << 2;
        const short8 bfrag = *(const short8*)((const char*)U16 + row * 128 + ((16 * lk) ^ ((row & 7) << 4)));
        unsigned int* srow = &S32[row * 64];
        unsigned int* U32  = (unsigned int*)U16;

#pragma unroll
        for (int nt = 0; nt < 4; ++nt) {
            short8 afr = *(const short8*)(WPPb + (nt * 16 + lr) * 32 + lk * 8);
            float4v acc = __builtin_amdgcn_mfma_f32_16x16x32_bf16(
                afr, bfrag, (float4v){0.f, 0.f, 0.f, 0.f}, 0, 0, 0);
            const int n0 = nt * 16 + lk * 4;
            if (n0 < 48) {
                uint2 v;
                v.x = cvtpk(fmaxf(acc[0], 0.f), fmaxf(acc[1], 0.f));
                v.y = cvtpk(fmaxf(acc[2], 0.f), fmaxf(acc[3], 0.f));
                *(uint2*)&srow[(26 + (n0 >> 1)) ^ swz4] = v;
            } else if (lk == 0) {
                srow[50 ^ swz4] = cvtpk(fmaxf(acc[0], 0.f), fmaxf(acc[1], 0.f));
            }
        }
#pragma unroll
        for (int nt = 0; nt < 4; ++nt) {
            short8 afr = *(const short8*)(WPAb + (nt * 16 + lr) * 32 + lk * 8);
            float4v acc = __builtin_amdgcn_mfma_f32_16x16x32_bf16(
                afr, bfrag, (float4v){0.f, 0.f, 0.f, 0.f}, 0, 0, 0);
            const int n0 = nt * 16 + lk * 4;
            if (n0 < 48) {
                uint2 v;
                v.x = cvtpk(fmaxf(acc[0], 0.f), fmaxf(acc[1], 0.f));
                v.y = cvtpk(fmaxf(acc[2], 0.f), fmaxf(acc[3], 0.f));
                *(uint2*)&U32[row * 32 + (((n0 >> 1)) ^ swz4)] = v;
            } else if (lk == 0) {
                U32[row * 32 + (24 ^ swz4)] = cvtpk(fmaxf(acc[0], 0.f), fmaxf(acc[1], 0.f));
            }
        }
    }

    // P GEMM: A = WPb tiles, B = S fragments; D[n][pair] -> float2 stores
    {
        const int row = 16 * w + lr;
        short8 sfrag[4];
        const char* srowb = (const char*)&S32[row * 64];
#pragma unroll
        for (int ks = 0; ks < 4; ++ks)
            sfrag[ks] = *(const short8*)(srowb + ((64 * ks + 16 * lk) ^ ((row & 7) << 4)));
        float* po = Pout + ((size_t)blk * 128 + row) * 50;
#pragma unroll
        for (int nt = 0; nt < 4; ++nt) {
            float4v acc = {0.f, 0.f, 0.f, 0.f};
#pragma unroll
            for (int ks = 0; ks < 4; ++ks) {
                short8 wf = *(const short8*)(WPb + (nt * 16 + lr) * 128 + ks * 32 + lk * 8);
                acc = __builtin_amdgcn_mfma_f32_16x16x32_bf16(wf, sfrag[ks], acc, 0, 0, 0);
            }
            const int n0 = nt * 16 + lk * 4;
            if (n0 < 48) {
                float2 v0 = {fmaxf(acc[0], 0.f), fmaxf(acc[1], 0.f)};
                float2 v1 = {fmaxf(acc[2], 0.f), fmaxf(acc[3], 0.f)};
                *(float2*)(po + n0)     = v0;
                *(float2*)(po + n0 + 2) = v1;
            } else if (lk == 0) {
                float2 v0 = {fmaxf(acc[0], 0.f), fmaxf(acc[1], 0.f)};
                *(float2*)(po + 48) = v0;
            }
        }
    }

    // segment-sum of PA; forced heads every 32 rows cap the serial walk
    __syncthreads();
    if (t < 128) {
        bool head = ((t & 31) == 0) || (ps_lds[t] != ps_lds[t - 1]);
        if (head) {
            int idx = atomicAdd(&nheads, 1);
            head_list[idx] = (unsigned char)t;
        }
    }
    __syncthreads();

    const int nh = nheads;
    const unsigned int* U32c = (const unsigned int*)U16;
    for (int iw = t; iw < nh * 25; iw += 512) {
        const int r0  = head_list[iw / 25];
        const int jc  = iw % 25;
        const int seg = ps_lds[r0];
        float a0 = 0.0f, a1 = 0.0f;
        int rr = r0;
        do {
            unsigned int u = U32c[rr * 32 + (jc ^ ((rr & 7) << 2))];
            a0 += bflo(u);
            a1 += bfhi(u);
            ++rr;
        } while (rr < 128 && (rr & 31) != 0 && ps_lds[rr] == seg);
        atomicAdd(&PAsum[(size_t)seg * 50 + 2 * jc],     a0);
        atomicAdd(&PAsum[(size_t)seg * 50 + 2 * jc + 1], a1);
    }
}

// K3: A = relu(concat(AA, PAsum) @ W_A.T + b_A). (2,2) — proven tier.
__global__ __launch_bounds__(256) __attribute__((amdgpu_waves_per_eu(2, 2)))
void k_atom_final(
    const float* __restrict__ AA, const float* __restrict__ PAsum,
    const float* __restrict__ W_A, const float* __restrict__ b_A,
    float* __restrict__ Aout)
{
    const int a = blockIdx.x * 256 + threadIdx.x;
    if (a >= NATOMS) return;
    const int o0 = blockIdx.y * 25;

    float v[100];
    {
        const float2* p1 = (const float2*)(AA + (size_t)a * 50);
        const float2* p2 = (const float2*)(PAsum + (size_t)a * 50);
#pragma unroll
        for (int q = 0; q < 25; ++q) {
            float2 u1 = p1[q], u2 = p2[q];
            v[2 * q] = u1.x;      v[2 * q + 1] = u1.y;
            v[50 + 2 * q] = u2.x; v[50 + 2 * q + 1] = u2.y;
        }
    }
    float* ao = Aout + (size_t)a * 50;
#pragma unroll 2
    for (int o = o0; o < o0 + 25; ++o) {
        const float4* w4 = (const float4*)(W_A + (size_t)o * 100);
        float acc = b_A[o];
#pragma unroll
        for (int q = 0; q < 25; ++q) {
            float4 w = w4[q];
            acc = fmaf(v[4 * q + 0], w.x, acc);
            acc = fmaf(v[4 * q + 1], w.y, acc);
            acc = fmaf(v[4 * q + 2], w.z, acc);
            acc = fmaf(v[4 * q + 3], w.w, acc);
        }
        ao[o] = fmaxf(acc, 0.0f);
    }
}

extern "C" void kernel_launch(void* const* d_in, const int* in_sizes, int n_in,
                              void* d_out, int out_size, void* d_ws, size_t ws_size,
                              hipStream_t stream)
{
    const float* atom_features = (const float*)d_in[0];
    const float* pair_features = (const float*)d_in[1];
    const int*   pair_split    = (const int*)d_in[2];
    const int*   atom_to_pair  = (const int*)d_in[3];
    const float* W_AA = (const float*)d_in[4];
    const float* b_AA = (const float*)d_in[5];
    const float* W_PA = (const float*)d_in[6];
    const float* b_PA = (const float*)d_in[7];
    const float* W_A  = (const float*)d_in[8];
    const float* b_A  = (const float*)d_in[9];
    const float* W_AP = (const float*)d_in[10];
    const float* b_AP = (const float*)d_in[11];
    const float* W_PP = (const float*)d_in[12];
    const float* b_PP = (const float*)d_in[13];
    const float* W_P  = (const float*)d_in[14];
    const float* b_P  = (const float*)d_in[15];

    float* out   = (float*)d_out;
    float* A_out = out;                              // [NATOMS,50]
    float* P_out = out + (size_t)NATOMS * 50;        // [NPAIRS,50]

    float*          AA    = (float*)d_ws;                                    // 20.0 MB
    unsigned short* XAu16 = (unsigned short*)(AA + (size_t)NATOMS * 50);     // 12.8 MB
    float*          PAsum = (float*)(XAu16 + (size_t)NATOMS * 64);           // 20.0 MB
    unsigned short* WPb   = (unsigned short*)(PAsum + (size_t)NATOMS * 50);  // 16 KB
    unsigned short* WPPb  = WPb + 64 * 128;
    unsigned short* WPAb  = WPPb + 64 * 32;

    k_wconv<<<256, 256, 0, stream>>>(W_P, b_P, W_PP, b_PP, W_PA, b_PA,
                                     WPb, WPPb, WPAb, PAsum);

    k_atom_pre<<<dim3(391, 2), 256, 0, stream>>>(
        atom_features, W_AA, b_AA, W_AP, b_AP, AA, XAu16);

    k_pair<<<NPAIRS / 128, 512, 0, stream>>>(
        pair_features, pair_split, atom_to_pair,
        WPb, WPPb, WPAb, XAu16, PAsum, P_out);

    k_atom_final<<<dim3(391, 2), 256, 0, stream>>>(
        AA, PAsum, W_A, b_A, A_out);
}

// Round 14
// 691.118 us; speedup vs baseline: 1.8290x; 1.3728x over previous
//
#include <hip/hip_runtime.h>

#define NATOMS 100000
#define NPAIRS 3200000
// F_ATOM=75, F_PAIR=14, H=50, F_OUT=50

using short8  = __attribute__((ext_vector_type(8))) short;
using float4v = __attribute__((ext_vector_type(4))) float;
using fx2     = __attribute__((ext_vector_type(2))) float;

__device__ __forceinline__ unsigned short f2bf(float f) {
    unsigned int u = __float_as_uint(f);
    unsigned int r = (u + 0x7fffu + ((u >> 16) & 1u)) >> 16;   // RNE
    return (unsigned short)r;
}
__device__ __forceinline__ float bflo(unsigned int u) { return __uint_as_float(u << 16); }
__device__ __forceinline__ float bfhi(unsigned int u) { return __uint_as_float(u & 0xffff0000u); }
// HW packed f32x2 -> bf16x2 (one VALU op)
__device__ __forceinline__ unsigned int cvtpk(float lo, float hi) {
    unsigned int r;
    asm("v_cvt_pk_bf16_f32 %0, %1, %2" : "=v"(r) : "v"(lo), "v"(hi));
    return r;
}

// software fp8 e4m3 OCP encode (fallback)
__device__ __forceinline__ unsigned int fp8e(float v) {
    unsigned int u = __float_as_uint(v);
    unsigned int a = u & 0x7fffffffu;
    unsigned int r = a + 0x7FFFFu + ((a >> 20) & 1u);
    int e8 = (int)(r >> 23) - 120;
    unsigned int b = (e8 >= 1) ? (((unsigned int)e8 << 3) | ((r >> 20) & 7u)) : 0u;
    return b | ((u >> 24) & 0x80u);
}

#if __has_builtin(__builtin_amdgcn_cvt_pk_fp8_f32)
__device__ __forceinline__ unsigned int enc4(float a, float b, float c, float d) {
    int w = __builtin_amdgcn_cvt_pk_fp8_f32(a, b, 0, false);
    w = __builtin_amdgcn_cvt_pk_fp8_f32(c, d, w, true);
    return (unsigned int)w;
}
__device__ __forceinline__ unsigned short enc2(float a, float b) {
    return (unsigned short)(__builtin_amdgcn_cvt_pk_fp8_f32(a, b, 0, false) & 0xffff);
}
#else
__device__ __forceinline__ unsigned int enc4(float a, float b, float c, float d) {
    return fp8e(a) | (fp8e(b) << 8) | (fp8e(c) << 16) | (fp8e(d) << 24);
}
__device__ __forceinline__ unsigned short enc2(float a, float b) {
    return (unsigned short)(fp8e(a) | (fp8e(b) << 8));
}
#endif

#if __has_builtin(__builtin_amdgcn_cvt_pk_f32_fp8)
__device__ __forceinline__ fx2 dec8lo(unsigned int u) { return __builtin_amdgcn_cvt_pk_f32_fp8((int)u, false); }
__device__ __forceinline__ fx2 dec8hi(unsigned int u) { return __builtin_amdgcn_cvt_pk_f32_fp8((int)u, true); }
#else
__device__ __forceinline__ float fp8d_(unsigned int u, int sh) {
    unsigned int b = (u >> sh) & 0xffu;
    return __uint_as_float((((b & 0x7fu) << 20) + 0x3C000000u) | ((b & 0x80u) << 24));
}
__device__ __forceinline__ fx2 dec8lo(unsigned int u) { fx2 r; r.x = fp8d_(u, 0);  r.y = fp8d_(u, 8);  return r; }
__device__ __forceinline__ fx2 dec8hi(unsigned int u) { fx2 r; r.x = fp8d_(u, 16); r.y = fp8d_(u, 24); return r; }
#endif

// ws: AAb u16[NATOMS*64] (bf16 AA) | XAu16 u16[NATOMS*64] (fp8 X1'@bytes0..49, X2@64..113)
//     PAsum f32[NATOMS*50] | WPb[64*128] | WPPb[64*32] | WPAb[64*32] | WATb[160*96] | WAb[64*128]

// K0: all weight tables + PAsum zeroing.
// WATb layout [n][96k]: n0..49 AA (W_AA, bias@k75), n52..101 X1 (W_AP[:, :75], b_AP@k75),
//   n104..153 X2 (W_AP[:, 75:], no bias), k76..95 zero, gap rows zero.
__global__ __launch_bounds__(256) void k_wconv(
    const float* __restrict__ W_P,  const float* __restrict__ b_P,
    const float* __restrict__ W_PP, const float* __restrict__ b_PP,
    const float* __restrict__ W_PA, const float* __restrict__ b_PA,
    const float* __restrict__ W_AA, const float* __restrict__ b_AA,
    const float* __restrict__ W_AP, const float* __restrict__ b_AP,
    const float* __restrict__ W_A,  const float* __restrict__ b_A,
    unsigned short* __restrict__ WPb,  unsigned short* __restrict__ WPPb,
    unsigned short* __restrict__ WPAb, unsigned short* __restrict__ WATb,
    unsigned short* __restrict__ WAb,  float* __restrict__ PAsum)
{
    const int idx = blockIdx.x * 256 + threadIdx.x;
    if (idx < 64 * 128) {
        const int n = idx >> 7, k = idx & 127;
        float v = 0.0f, va = 0.0f;
        if (n < 50) {
            if (k < 50)                  { v = W_P[n * 100 + k];            va = W_A[n * 100 + k]; }
            else if (k == 50)            { v = b_P[n];                      va = b_A[n]; }
            else if (k >= 52 && k < 102) { v = W_P[n * 100 + 50 + (k - 52)]; va = W_A[n * 100 + 50 + (k - 52)]; }
        }
        WPb[idx] = f2bf(v);
        WAb[idx] = f2bf(va);
    }
    if (idx < 64 * 32) {
        const int n = idx >> 5, k = idx & 31;
        float vp = 0.0f, va = 0.0f;
        if (n < 50) {
            if (k < 14)      { vp = W_PP[n * 14 + k]; va = W_PA[n * 14 + k]; }
            else if (k == 14){ vp = b_PP[n];          va = b_PA[n]; }
        }
        WPPb[idx] = f2bf(vp);
        WPAb[idx] = f2bf(va);
    }
    if (idx < 160 * 96) {
        const int n = idx / 96, k = idx - n * 96;
        float v = 0.0f;
        if (n < 50) {                       // AA section
            if (k < 75)       v = W_AA[n * 75 + k];
            else if (k == 75) v = b_AA[n];
        } else if (n >= 52 && n < 102) {    // X1 section
            if (k < 75)       v = W_AP[(n - 52) * 150 + k];
            else if (k == 75) v = b_AP[n - 52];
        } else if (n >= 104 && n < 154) {   // X2 section
            if (k < 75)       v = W_AP[(n - 104) * 150 + 75 + k];
        }
        WATb[idx] = f2bf(v);
    }
    for (int i = idx; i < NATOMS * 50; i += 256 * 256) PAsum[i] = 0.0f;
}

// K1: per-atom precompute via MFMA. 512 thr = 8 waves, 128 atoms/block,
// wave w owns rows [16w,16w+16) — staging is wave-local, zero barriers.
// af staged bf16 into LDS [128][128 u16] (256B rows, XOR swizzle), k75 = 1.0 bias slot.
// 10 n-tiles x 3 k-steps = 30 MFMA/wave; epilogue: AA->bf16, X1/X2->fp8.
__global__ __launch_bounds__(512) void k_atom_pre(
    const float* __restrict__ af,
    const unsigned short* __restrict__ WATb,
    unsigned short* __restrict__ AAb,
    unsigned short* __restrict__ XAu16)
{
    __shared__ unsigned short U16[128 * 128];   // 32 KB

    const int t   = threadIdx.x;
    const int blk = blockIdx.x;
    const int pl  = t >> 2;
    const int sub = t & 3;
    const int w   = t >> 6;
    const int l   = t & 63;
    const int lr  = l & 15;
    const int lk  = l >> 4;
    const int a0  = blk * 128;

    // ---- stage af row pl (bf16, k75 = 1.0, k76..127 = 0) ----
    {
        const int a = a0 + pl;
        const int swz = (pl & 7) << 2;                 // u32-slot swizzle
        unsigned int* urow = (unsigned int*)U16 + pl * 64;
        if (a < NATOMS) {
            const float* ar = af + (size_t)a * 75;
            if (sub < 3) {
                const int c0 = sub * 20;
#pragma unroll
                for (int q = 0; q < 10; ++q)
                    urow[(c0 / 2 + q) ^ swz] = cvtpk(ar[c0 + 2 * q], ar[c0 + 2 * q + 1]);
            } else {
#pragma unroll
                for (int q = 0; q < 7; ++q)
                    urow[(30 + q) ^ swz] = cvtpk(ar[60 + 2 * q], ar[60 + 2 * q + 1]);
                urow[37 ^ swz] = cvtpk(ar[74], 1.0f);
            }
        } else {
            if (sub < 3) {
                const int c0 = sub * 20;
#pragma unroll
                for (int q = 0; q < 10; ++q) urow[(c0 / 2 + q) ^ swz] = 0u;
            } else {
#pragma unroll
                for (int q = 30; q <= 37; ++q) urow[q ^ swz] = 0u;
            }
        }
        if (sub == 3) {
#pragma unroll
            for (int q = 38; q < 48; ++q) urow[q ^ swz] = 0u;
        }
#pragma unroll
        for (int q = 48 + sub; q < 64; q += 4) urow[q ^ swz] = 0u;
    }

    // ---- MFMA: A = WATb tiles, B = af fragments ----
    {
        const int row  = 16 * w + lr;
        const int aat  = a0 + row;
        const int swzb = (row & 7) << 4;
        const char* ub = (const char*)U16 + row * 256;
        short8 bf0 = *(const short8*)(ub + ((0   + lk * 16) ^ swzb));
        short8 bf1 = *(const short8*)(ub + ((64  + lk * 16) ^ swzb));
        short8 bf2 = *(const short8*)(ub + ((128 + lk * 16) ^ swzb));

#pragma unroll
        for (int nt = 0; nt < 10; ++nt) {
            float4v acc = {0.f, 0.f, 0.f, 0.f};
            const unsigned short* wr = WATb + (nt * 16 + lr) * 96 + lk * 8;
            acc = __builtin_amdgcn_mfma_f32_16x16x32_bf16(*(const short8*)(wr),      bf0, acc, 0, 0, 0);
            acc = __builtin_amdgcn_mfma_f32_16x16x32_bf16(*(const short8*)(wr + 32), bf1, acc, 0, 0, 0);
            acc = __builtin_amdgcn_mfma_f32_16x16x32_bf16(*(const short8*)(wr + 64), bf2, acc, 0, 0, 0);
            const int n0 = nt * 16 + lk * 4;
            if (aat < NATOMS) {
                if (n0 <= 48) {                      // AA (relu, bf16)
                    if (n0 < 48) {
                        uint2 v;
                        v.x = cvtpk(fmaxf(acc[0], 0.f), fmaxf(acc[1], 0.f));
                        v.y = cvtpk(fmaxf(acc[2], 0.f), fmaxf(acc[3], 0.f));
                        *(uint2*)(AAb + (size_t)aat * 64 + n0) = v;
                    } else {
                        *(unsigned int*)(AAb + (size_t)aat * 64 + 48) =
                            cvtpk(fmaxf(acc[0], 0.f), fmaxf(acc[1], 0.f));
                    }
                } else if (n0 >= 52 && n0 <= 100) {  // X1 (raw, fp8)
                    char* xb = (char*)XAu16 + (size_t)aat * 128;
                    if (n0 < 100) *(unsigned int*)(xb + (n0 - 52)) = enc4(acc[0], acc[1], acc[2], acc[3]);
                    else          *(unsigned short*)(xb + 48)      = enc2(acc[0], acc[1]);
                } else if (n0 >= 104 && n0 <= 152) { // X2 (raw, fp8)
                    char* xb = (char*)XAu16 + (size_t)aat * 128 + 64;
                    if (n0 < 152) *(unsigned int*)(xb + (n0 - 104)) = enc4(acc[0], acc[1], acc[2], acc[3]);
                    else          *(unsigned short*)(xb + 48)       = enc2(acc[0], acc[1]);
                }
            }
        }
    }
}

// one u32 (4 fp8 per stream) -> 2 swizzled bf16-pair slots
__device__ __forceinline__ void s_pair_u32(unsigned int x1i, unsigned int x2j,
    unsigned int x1j, unsigned int x2i, unsigned int* srow, int slot, int swz)
{
    fx2 aL = dec8lo(x1i), bL = dec8lo(x2j), cL = dec8lo(x1j), dL = dec8lo(x2i);
    fx2 aH = dec8hi(x1i), bH = dec8hi(x2j), cH = dec8hi(x1j), dH = dec8hi(x2i);
    float sL0 = fmaxf(aL.x + bL.x, 0.f) + fmaxf(cL.x + dL.x, 0.f);
    float sL1 = fmaxf(aL.y + bL.y, 0.f) + fmaxf(cL.y + dL.y, 0.f);
    float sH0 = fmaxf(aH.x + bH.x, 0.f) + fmaxf(cH.x + dH.x, 0.f);
    float sH1 = fmaxf(aH.y + bH.y, 0.f) + fmaxf(cH.y + dH.y, 0.f);
    srow[(slot)     ^ swz] = cvtpk(sL0, sL1);
    srow[(slot + 1) ^ swz] = cvtpk(sH0, sH1);
}
__device__ __forceinline__ void s_chunk16(uint4 X1i, uint4 X2j, uint4 X1j, uint4 X2i,
                                          int c, unsigned int* srow, int swz)
{
    const int o = 8 * c;
    s_pair_u32(X1i.x, X2j.x, X1j.x, X2i.x, srow, o + 0, swz);
    s_pair_u32(X1i.y, X2j.y, X1j.y, X2i.y, srow, o + 2, swz);
    s_pair_u32(X1i.z, X2j.z, X1j.z, X2i.z, srow, o + 4, swz);
    s_pair_u32(X1i.w, X2j.w, X1j.w, X2i.w, srow, o + 6, swz);
}

// K2: MFMA pair kernel (unchanged from round 13).
__global__ __launch_bounds__(512) void k_pair(
    const float* __restrict__ pf,
    const int* __restrict__ psplit,
    const int* __restrict__ a2p,
    const unsigned short* __restrict__ WPb,
    const unsigned short* __restrict__ WPPb,
    const unsigned short* __restrict__ WPAb,
    const unsigned short* __restrict__ XAu16,
    float* __restrict__ PAsum,
    float* __restrict__ Pout)
{
    __shared__ unsigned int  S32[128 * 64];   // 32 KB
    __shared__ unsigned short U16[128 * 64];  // 16 KB
    __shared__ int ps_lds[128];
    __shared__ unsigned char head_list[128];
    __shared__ int nheads;

    const int t   = threadIdx.x;
    const int blk = blockIdx.x;
    const int pl  = t >> 2;
    const int sub = t & 3;
    const int p   = blk * 128 + pl;   // NPAIRS == 25000*128
    const int w   = t >> 6;
    const int l   = t & 63;
    const int lr  = l & 15;
    const int lk  = l >> 4;

    if (t == 0) nheads = 0;
    if (t < 128) ps_lds[t] = psplit[blk * 128 + t];

    const int2 ij = ((const int2*)a2p)[p];
    float2 pfa, pfb, pfc, pfd;
    {
        const float2* pr2 = (const float2*)(pf + (size_t)p * 14);
        if (sub == 0) { pfa = pr2[0]; pfb = pr2[1]; pfc = pr2[2]; pfd = pr2[3]; }
        else if (sub == 1) { pfa = pr2[4]; pfb = pr2[5]; pfc = pr2[6]; }
    }

    const uint4* xi4 = (const uint4*)(XAu16 + (size_t)ij.x * 64);
    const uint4* xj4 = (const uint4*)(XAu16 + (size_t)ij.y * 64);
    uint4 X1i, X1j, X2i, X2j;
    unsigned int t12i = 0, t12j = 0, t28i = 0, t28j = 0;
    if (sub < 3) {
        X1i = xi4[sub];     X1j = xj4[sub];
        X2i = xi4[4 + sub]; X2j = xj4[4 + sub];
    } else {
        const unsigned int* xiu = (const unsigned int*)xi4;
        const unsigned int* xju = (const unsigned int*)xj4;
        t12i = xiu[12]; t12j = xju[12];
        t28i = xiu[28]; t28j = xju[28];
    }

    {
        uint4 q = {0u, 0u, 0u, 0u};
        if (sub == 0) {
            q.x = cvtpk(pfa.x, pfa.y); q.y = cvtpk(pfb.x, pfb.y);
            q.z = cvtpk(pfc.x, pfc.y); q.w = cvtpk(pfd.x, pfd.y);
        } else if (sub == 1) {
            q.x = cvtpk(pfa.x, pfa.y); q.y = cvtpk(pfb.x, pfb.y);
            q.z = cvtpk(pfc.x, pfc.y); q.w = 0x00003F80u;
        }
        *(uint4*)((char*)U16 + pl * 128 + ((16 * sub) ^ ((pl & 7) << 4))) = q;
    }

    {
        unsigned int* srow = &S32[pl * 64];
        const int swz = (pl & 7) << 2;
        if (sub < 3) {
            s_chunk16(X1i, X2j, X1j, X2i, sub, srow, swz);
        } else {
            fx2 aL = dec8lo(t12i), bL = dec8lo(t28j), cL = dec8lo(t12j), dL = dec8lo(t28i);
            float s48 = fmaxf(aL.x + bL.x, 0.f) + fmaxf(cL.x + dL.x, 0.f);
            float s49 = fmaxf(aL.y + bL.y, 0.f) + fmaxf(cL.y + dL.y, 0.f);
            srow[24 ^ swz] = cvtpk(s48, s49);
            srow[25 ^ swz] = 0x00003F80u;
#pragma unroll
            for (int u = 51; u <= 63; ++u) srow[u ^ swz] = 0u;
        }
    }

    {
        const int row  = 16 * w + lr;
        const int swz4 = (row & 7) << 2;
        const short8 bfrag = *(const short8*)((const char*)U16 + row * 128 + ((16 * lk) ^ ((row & 7) << 4)));
        unsigned int* srow = &S32[row * 64];
        unsigned int* U32  = (unsigned int*)U16;

#pragma unroll
        for (int nt = 0; nt < 4; ++nt) {
            short8 afr = *(const short8*)(WPPb + (nt * 16 + lr) * 32 + lk * 8);
            float4v acc = __builtin_amdgcn_mfma_f32_16x16x32_bf16(
                afr, bfrag, (float4v){0.f, 0.f, 0.f, 0.f}, 0, 0, 0);
            const int n0 = nt * 16 + lk * 4;
            if (n0 < 48) {
                uint2 v;
                v.x = cvtpk(fmaxf(acc[0], 0.f), fmaxf(acc[1], 0.f));
                v.y = cvtpk(fmaxf(acc[2], 0.f), fmaxf(acc[3], 0.f));
                *(uint2*)&srow[(26 + (n0 >> 1)) ^ swz4] = v;
            } else if (lk == 0) {
                srow[50 ^ swz4] = cvtpk(fmaxf(acc[0], 0.f), fmaxf(acc[1], 0.f));
            }
        }
#pragma unroll
        for (int nt = 0; nt < 4; ++nt) {
            short8 afr = *(const short8*)(WPAb + (nt * 16 + lr) * 32 + lk * 8);
            float4v acc = __builtin_amdgcn_mfma_f32_16x16x32_bf16(
                afr, bfrag, (float4v){0.f, 0.f, 0.f, 0.f}, 0, 0, 0);
            const int n0 = nt * 16 + lk * 4;
            if (n0 < 48) {
                uint2 v;
                v.x = cvtpk(fmaxf(acc[0], 0.f), fmaxf(acc[1], 0.f));
                v.y = cvtpk(fmaxf(acc[2], 0.f), fmaxf(acc[3], 0.f));
                *(uint2*)&U32[row * 32 + (((n0 >> 1)) ^ swz4)] = v;
            } else if (lk == 0) {
                U32[row * 32 + (24 ^ swz4)] = cvtpk(fmaxf(acc[0], 0.f), fmaxf(acc[1], 0.f));
            }
        }
    }

    {
        const int row = 16 * w + lr;
        short8 sfrag[4];
        const char* srowb = (const char*)&S32[row * 64];
#pragma unroll
        for (int ks = 0; ks < 4; ++ks)
            sfrag[ks] = *(const short8*)(srowb + ((64 * ks + 16 * lk) ^ ((row & 7) << 4)));
        float* po = Pout + ((size_t)blk * 128 + row) * 50;
#pragma unroll
        for (int nt = 0; nt < 4; ++nt) {
            float4v acc = {0.f, 0.f, 0.f, 0.f};
#pragma unroll
            for (int ks = 0; ks < 4; ++ks) {
                short8 wf = *(const short8*)(WPb + (nt * 16 + lr) * 128 + ks * 32 + lk * 8);
                acc = __builtin_amdgcn_mfma_f32_16x16x32_bf16(wf, sfrag[ks], acc, 0, 0, 0);
            }
            const int n0 = nt * 16 + lk * 4;
            if (n0 < 48) {
                float2 v0 = {fmaxf(acc[0], 0.f), fmaxf(acc[1], 0.f)};
                float2 v1 = {fmaxf(acc[2], 0.f), fmaxf(acc[3], 0.f)};
                *(float2*)(po + n0)     = v0;
                *(float2*)(po + n0 + 2) = v1;
            } else if (lk == 0) {
                float2 v0 = {fmaxf(acc[0], 0.f), fmaxf(acc[1], 0.f)};
                *(float2*)(po + 48) = v0;
            }
        }
    }

    __syncthreads();
    if (t < 128) {
        bool head = ((t & 31) == 0) || (ps_lds[t] != ps_lds[t - 1]);
        if (head) {
            int idx = atomicAdd(&nheads, 1);
            head_list[idx] = (unsigned char)t;
        }
    }
    __syncthreads();

    const int nh = nheads;
    const unsigned int* U32c = (const unsigned int*)U16;
    for (int iw = t; iw < nh * 25; iw += 512) {
        const int r0  = head_list[iw / 25];
        const int jc  = iw % 25;
        const int seg = ps_lds[r0];
        float a0 = 0.0f, a1 = 0.0f;
        int rr = r0;
        do {
            unsigned int u = U32c[rr * 32 + (jc ^ ((rr & 7) << 2))];
            a0 += bflo(u);
            a1 += bfhi(u);
            ++rr;
        } while (rr < 128 && (rr & 31) != 0 && ps_lds[rr] == seg);
        atomicAdd(&PAsum[(size_t)seg * 50 + 2 * jc],     a0);
        atomicAdd(&PAsum[(size_t)seg * 50 + 2 * jc + 1], a1);
    }
}

// K3: A = relu([AA, PAsum] @ W_A.T + b_A) via MFMA. Same structure as k_atom_pre;
// K=128 (k0..49 AA bf16, k50=1.0 bias, k52..101 PAsum->bf16), 4 nt x 4 ks.
__global__ __launch_bounds__(512) void k_atom_final(
    const unsigned short* __restrict__ AAb,
    const float* __restrict__ PAsum,
    const unsigned short* __restrict__ WAb,
    float* __restrict__ Aout)
{
    __shared__ unsigned short U16[128 * 128];   // 32 KB

    const int t   = threadIdx.x;
    const int blk = blockIdx.x;
    const int pl  = t >> 2;
    const int sub = t & 3;
    const int w   = t >> 6;
    const int l   = t & 63;
    const int lr  = l & 15;
    const int lk  = l >> 4;
    const int a0  = blk * 128;

    // ---- stage row pl ----
    {
        const int a = a0 + pl;
        const int swz = (pl & 7) << 2;
        unsigned int* urow = (unsigned int*)U16 + pl * 64;
        if (a < NATOMS) {
            const unsigned int* aab = (const unsigned int*)AAb + (size_t)a * 32;
            if (sub < 3) {
#pragma unroll
                for (int q = 0; q < 7; ++q) urow[(7 * sub + q) ^ swz] = aab[7 * sub + q];
            } else {
#pragma unroll
                for (int q = 21; q < 25; ++q) urow[q ^ swz] = aab[q];
                urow[25 ^ swz] = 0x00003F80u;   // k50=1.0, k51=0
            }
            const float* ps = PAsum + (size_t)a * 50;
            const int c0 = 14 * sub;
            const int np = (sub < 3) ? 7 : 4;
#pragma unroll
            for (int q = 0; q < 7; ++q) {
                if (q < np)
                    urow[(26 + c0 / 2 + q) ^ swz] = cvtpk(ps[c0 + 2 * q], ps[c0 + 2 * q + 1]);
            }
        } else {
            if (sub < 3) {
#pragma unroll
                for (int q = 0; q < 7; ++q) { urow[(7 * sub + q) ^ swz] = 0u; urow[(26 + 7 * sub + q) ^ swz] = 0u; }
            } else {
#pragma unroll
                for (int q = 21; q < 26; ++q) urow[q ^ swz] = 0u;
#pragma unroll
                for (int q = 47; q < 51; ++q) urow[q ^ swz] = 0u;
            }
        }
#pragma unroll
        for (int q = 51 + sub; q < 64; q += 4) urow[q ^ swz] = 0u;
    }

    // ---- MFMA ----
    {
        const int row  = 16 * w + lr;
        const int aat  = a0 + row;
        const int swzb = (row & 7) << 4;
        const char* ub = (const char*)U16 + row * 256;
        short8 bf[4];
#pragma unroll
        for (int ks = 0; ks < 4; ++ks)
            bf[ks] = *(const short8*)(ub + ((ks * 64 + lk * 16) ^ swzb));

        float* ao = Aout + (size_t)aat * 50;
#pragma unroll
        for (int nt = 0; nt < 4; ++nt) {
            float4v acc = {0.f, 0.f, 0.f, 0.f};
#pragma unroll
            for (int ks = 0; ks < 4; ++ks) {
                short8 wf = *(const short8*)(WAb + (nt * 16 + lr) * 128 + ks * 32 + lk * 8);
                acc = __builtin_amdgcn_mfma_f32_16x16x32_bf16(wf, bf[ks], acc, 0, 0, 0);
            }
            const int n0 = nt * 16 + lk * 4;
            if (aat < NATOMS) {
                if (n0 < 48) {
                    float2 v0 = {fmaxf(acc[0], 0.f), fmaxf(acc[1], 0.f)};
                    float2 v1 = {fmaxf(acc[2], 0.f), fmaxf(acc[3], 0.f)};
                    *(float2*)(ao + n0)     = v0;
                    *(float2*)(ao + n0 + 2) = v1;
                } else if (lk == 0 && nt == 3) {
                    float2 v0 = {fmaxf(acc[0], 0.f), fmaxf(acc[1], 0.f)};
                    *(float2*)(ao + 48) = v0;
                }
            }
        }
    }
}

extern "C" void kernel_launch(void* const* d_in, const int* in_sizes, int n_in,
                              void* d_out, int out_size, void* d_ws, size_t ws_size,
                              hipStream_t stream)
{
    const float* atom_features = (const float*)d_in[0];
    const float* pair_features = (const float*)d_in[1];
    const int*   pair_split    = (const int*)d_in[2];
    const int*   atom_to_pair  = (const int*)d_in[3];
    const float* W_AA = (const float*)d_in[4];
    const float* b_AA = (const float*)d_in[5];
    const float* W_PA = (const float*)d_in[6];
    const float* b_PA = (const float*)d_in[7];
    const float* W_A  = (const float*)d_in[8];
    const float* b_A  = (const float*)d_in[9];
    const float* W_AP = (const float*)d_in[10];
    const float* b_AP = (const float*)d_in[11];
    const float* W_PP = (const float*)d_in[12];
    const float* b_PP = (const float*)d_in[13];
    const float* W_P  = (const float*)d_in[14];
    const float* b_P  = (const float*)d_in[15];

    float* out   = (float*)d_out;
    float* A_out = out;                              // [NATOMS,50]
    float* P_out = out + (size_t)NATOMS * 50;        // [NPAIRS,50]

    unsigned short* AAb   = (unsigned short*)d_ws;                           // 12.8 MB
    unsigned short* XAu16 = AAb + (size_t)NATOMS * 64;                       // 12.8 MB
    float*          PAsum = (float*)(XAu16 + (size_t)NATOMS * 64);           // 20.0 MB
    unsigned short* WPb   = (unsigned short*)(PAsum + (size_t)NATOMS * 50);
    unsigned short* WPPb  = WPb + 64 * 128;
    unsigned short* WPAb  = WPPb + 64 * 32;
    unsigned short* WATb  = WPAb + 64 * 32;
    unsigned short* WAb   = WATb + 160 * 96;

    k_wconv<<<256, 256, 0, stream>>>(W_P, b_P, W_PP, b_PP, W_PA, b_PA,
                                     W_AA, b_AA, W_AP, b_AP, W_A, b_A,
                                     WPb, WPPb, WPAb, WATb, WAb, PAsum);

    k_atom_pre<<<(NATOMS + 127) / 128, 512, 0, stream>>>(
        atom_features, WATb, AAb, XAu16);

    k_pair<<<NPAIRS / 128, 512, 0, stream>>>(
        pair_features, pair_split, atom_to_pair,
        WPb, WPPb, WPAb, XAu16, PAsum, P_out);

    k_atom_final<<<(NATOMS + 127) / 128, 512, 0, stream>>>(
        AAb, PAsum, WAb, A_out);
}